// Round 1
// baseline (167.321 us; speedup 1.0000x reference)
//
#include <hip/hip_runtime.h>
#include <stdint.h>

#define N_COLS 8192
#define N_ROWS 8192
#define FP8_MAX_F 448.0f
#define EPS_F 1e-12f

// Fake-quantize one value: scale, saturating clip, e4m3fn RNE cast (HW), dequant.
static __device__ __forceinline__ float fakequant(float x, float s) {
    float xs = x * s;
    xs = fminf(fmaxf(xs, -FP8_MAX_F), FP8_MAX_F);
    // gfx950 OCP e4m3fn convert, round-to-nearest-even, subnormal-correct.
    int p = __builtin_amdgcn_cvt_pk_fp8_f32(xs, xs, 0, false);
    float q = __builtin_amdgcn_cvt_f32_fp8(p, 0);
    return q / s;   // true IEEE divide to match numpy bit-exactly
}

__global__ __launch_bounds__(256) void zero_ws_kernel(uint32_t* __restrict__ amax) {
    int i = blockIdx.x * 256 + threadIdx.x;
    if (i < N_COLS) amax[i] = 0u;
}

// grid = (N_COLS/1024, ROWCHUNKS); each block: 256 threads x float4 = 1024 cols,
// rows_per_block rows. Per-thread running max of |x| as uint bits, then 4 atomics.
__global__ __launch_bounds__(256) void col_amax_kernel(const float4* __restrict__ x4,
                                                       uint32_t* __restrict__ amax,
                                                       int rows_per_block) {
    const int C4 = N_COLS / 4;
    int c4 = blockIdx.x * 256 + threadIdx.x;           // float4-column index
    int r0 = blockIdx.y * rows_per_block;
    uint32_t m0 = 0, m1 = 0, m2 = 0, m3 = 0;
    const float4* p = x4 + (size_t)r0 * C4 + c4;
    for (int r = 0; r < rows_per_block; ++r) {
        float4 v = p[(size_t)r * C4];
        m0 = max(m0, __float_as_uint(v.x) & 0x7FFFFFFFu);
        m1 = max(m1, __float_as_uint(v.y) & 0x7FFFFFFFu);
        m2 = max(m2, __float_as_uint(v.z) & 0x7FFFFFFFu);
        m3 = max(m3, __float_as_uint(v.w) & 0x7FFFFFFFu);
    }
    int c = c4 * 4;
    atomicMax((unsigned int*)&amax[c + 0], m0);
    atomicMax((unsigned int*)&amax[c + 1], m1);
    atomicMax((unsigned int*)&amax[c + 2], m2);
    atomicMax((unsigned int*)&amax[c + 3], m3);
}

__global__ __launch_bounds__(256) void scale_kernel(const uint32_t* __restrict__ amax,
                                                    float* __restrict__ scale) {
    int c = blockIdx.x * 256 + threadIdx.x;
    if (c < N_COLS) {
        float a = __uint_as_float(amax[c]);
        a = fmaxf(a, EPS_F);
        scale[c] = FP8_MAX_F / a;   // IEEE divide, matches numpy
    }
}

__global__ __launch_bounds__(256) void quant_kernel(const float4* __restrict__ x4,
                                                    const float4* __restrict__ scale4,
                                                    float4* __restrict__ out4,
                                                    size_t n4) {
    const int C4 = N_COLS / 4;
    size_t stride = (size_t)gridDim.x * 256;
    for (size_t i = (size_t)blockIdx.x * 256 + threadIdx.x; i < n4; i += stride) {
        float4 s = scale4[i & (size_t)(C4 - 1)];
        float4 v = x4[i];
        float4 o;
        o.x = fakequant(v.x, s.x);
        o.y = fakequant(v.y, s.y);
        o.z = fakequant(v.z, s.z);
        o.w = fakequant(v.w, s.w);
        out4[i] = o;
    }
}

extern "C" void kernel_launch(void* const* d_in, const int* in_sizes, int n_in,
                              void* d_out, int out_size, void* d_ws, size_t ws_size,
                              hipStream_t stream) {
    const float* x = (const float*)d_in[0];
    float* out = (float*)d_out;
    uint32_t* amax = (uint32_t*)d_ws;                                   // 8192 u32
    float* scale = (float*)((char*)d_ws + N_COLS * sizeof(uint32_t));   // 8192 f32

    zero_ws_kernel<<<N_COLS / 256, 256, 0, stream>>>(amax);

    const int ROWCHUNKS = 128;                      // 1024 blocks total
    dim3 g1(N_COLS / 1024, ROWCHUNKS);
    col_amax_kernel<<<g1, 256, 0, stream>>>((const float4*)x, amax,
                                            N_ROWS / ROWCHUNKS);

    scale_kernel<<<N_COLS / 256, 256, 0, stream>>>(amax, scale);

    size_t n4 = (size_t)N_ROWS * N_COLS / 4;
    quant_kernel<<<2048, 256, 0, stream>>>((const float4*)x, (const float4*)scale,
                                           (float4*)out, n4);
}

// Round 3
// 150.789 us; speedup vs baseline: 1.1096x; 1.1096x over previous
//
#include <hip/hip_runtime.h>
#include <stdint.h>

#define N_COLS 8192
#define N_ROWS 8192
#define C4 (N_COLS / 4)
#define FP8_MAX_F 448.0f
#define EPS_F 1e-12f
#define ROWCHUNKS 128
#define ROWS_PER_BLOCK (N_ROWS / ROWCHUNKS)   // 64

typedef float floatx4 __attribute__((ext_vector_type(4)));   // native vec for nt-store

// ---------------------------------------------------------------------------
// Pass 1: per-(rowchunk, column) partial abs-max. No atomics, no init needed.
// grid (8, 128) x 256 threads; each thread owns 4 columns x 64 rows.
// ---------------------------------------------------------------------------
__global__ __launch_bounds__(256) void col_amax_partial(const float4* __restrict__ x4,
                                                        float4* __restrict__ partial4) {
    int c4 = blockIdx.x * 256 + threadIdx.x;
    const float4* p = x4 + (size_t)blockIdx.y * ROWS_PER_BLOCK * C4 + c4;
    uint32_t m0 = 0, m1 = 0, m2 = 0, m3 = 0;   // |x| bit-pattern max == float max
#pragma unroll 8
    for (int r = 0; r < ROWS_PER_BLOCK; ++r) {
        float4 v = p[(size_t)r * C4];
        m0 = max(m0, __float_as_uint(v.x) & 0x7FFFFFFFu);
        m1 = max(m1, __float_as_uint(v.y) & 0x7FFFFFFFu);
        m2 = max(m2, __float_as_uint(v.z) & 0x7FFFFFFFu);
        m3 = max(m3, __float_as_uint(v.w) & 0x7FFFFFFFu);
    }
    float4 o;
    o.x = __uint_as_float(m0);
    o.y = __uint_as_float(m1);
    o.z = __uint_as_float(m2);
    o.w = __uint_as_float(m3);
    partial4[(size_t)blockIdx.y * C4 + c4] = o;
}

// ---------------------------------------------------------------------------
// Pass 2: reduce 128 partials per column; emit bit-exact forward scale
// (IEEE 448/amax, matches numpy) and the dequant inverse (amax/448).
// ---------------------------------------------------------------------------
__global__ __launch_bounds__(256) void scale_from_partials(const float* __restrict__ partial,
                                                           float* __restrict__ scale,
                                                           float* __restrict__ inv) {
    int c = blockIdx.x * 256 + threadIdx.x;
    float a = 0.0f;
#pragma unroll 8
    for (int k = 0; k < ROWCHUNKS; ++k)
        a = fmaxf(a, partial[(size_t)k * N_COLS + c]);
    a = fmaxf(a, EPS_F);
    scale[c] = FP8_MAX_F / a;   // IEEE divide: must be bit-identical to numpy
    inv[c]   = a / FP8_MAX_F;   // dequant multiplier (1-2 ulp vs q/scale: fine)
}

// ---------------------------------------------------------------------------
// Pass 3: scale -> clip -> HW e4m3fn RNE cast -> dequant-multiply.
// Non-temporal stores so `out` doesn't evict x from the 256 MiB L3.
// ---------------------------------------------------------------------------
__global__ __launch_bounds__(256) void quant_kernel(const float4* __restrict__ x4,
                                                    const float4* __restrict__ scale4,
                                                    const float4* __restrict__ inv4,
                                                    floatx4* __restrict__ out4) {
    const size_t n4 = (size_t)N_ROWS * C4;
    size_t stride = (size_t)gridDim.x * 256;
    for (size_t i = (size_t)blockIdx.x * 256 + threadIdx.x; i < n4; i += stride) {
        size_t ci = i & (size_t)(C4 - 1);
        float4 s = scale4[ci];
        float4 w = inv4[ci];
        float4 v = x4[i];
        float a0 = fminf(fmaxf(v.x * s.x, -FP8_MAX_F), FP8_MAX_F);
        float a1 = fminf(fmaxf(v.y * s.y, -FP8_MAX_F), FP8_MAX_F);
        float a2 = fminf(fmaxf(v.z * s.z, -FP8_MAX_F), FP8_MAX_F);
        float a3 = fminf(fmaxf(v.w * s.w, -FP8_MAX_F), FP8_MAX_F);
        int p = __builtin_amdgcn_cvt_pk_fp8_f32(a0, a1, 0, false);
        p = __builtin_amdgcn_cvt_pk_fp8_f32(a2, a3, p, true);
        floatx4 o;
        o.x = __builtin_amdgcn_cvt_f32_fp8(p, 0) * w.x;
        o.y = __builtin_amdgcn_cvt_f32_fp8(p, 1) * w.y;
        o.z = __builtin_amdgcn_cvt_f32_fp8(p, 2) * w.z;
        o.w = __builtin_amdgcn_cvt_f32_fp8(p, 3) * w.w;
        __builtin_nontemporal_store(o, &out4[i]);
    }
}

extern "C" void kernel_launch(void* const* d_in, const int* in_sizes, int n_in,
                              void* d_out, int out_size, void* d_ws, size_t ws_size,
                              hipStream_t stream) {
    const float* x = (const float*)d_in[0];
    float* out = (float*)d_out;
    // ws: partial (128*8192 f32 = 4 MB) | scale (32 KB) | inv (32 KB)
    float* partial = (float*)d_ws;
    float* scale = (float*)((char*)d_ws + (size_t)ROWCHUNKS * N_COLS * sizeof(float));
    float* inv = scale + N_COLS;

    dim3 g1(N_COLS / 1024, ROWCHUNKS);
    col_amax_partial<<<g1, 256, 0, stream>>>((const float4*)x, (float4*)partial);

    scale_from_partials<<<N_COLS / 256, 256, 0, stream>>>(partial, scale, inv);

    quant_kernel<<<2048, 256, 0, stream>>>((const float4*)x, (const float4*)scale,
                                           (const float4*)inv, (floatx4*)out);
}

// Round 4
// 149.197 us; speedup vs baseline: 1.1215x; 1.0107x over previous
//
#include <hip/hip_runtime.h>
#include <stdint.h>

#define N_COLS 8192
#define N_ROWS 8192
#define C4 (N_COLS / 4)
#define FP8_MAX_F 448.0f
#define EPS_F 1e-12f
#define ROWCHUNKS 128
#define ROWS_PER_BLOCK (N_ROWS / ROWCHUNKS)   // 64
#define QBLOCKS 2048

typedef float floatx4 __attribute__((ext_vector_type(4)));   // native vec for nt-store

// ---------------------------------------------------------------------------
// Pass 1: per-(rowchunk, column) partial abs-max. Forward stream over x
// (populates L3; tail of x is hottest when this pass finishes).
// ---------------------------------------------------------------------------
__global__ __launch_bounds__(256) void col_amax_partial(const float4* __restrict__ x4,
                                                        float4* __restrict__ partial4) {
    int c4 = blockIdx.x * 256 + threadIdx.x;
    const float4* p = x4 + (size_t)blockIdx.y * ROWS_PER_BLOCK * C4 + c4;
    uint32_t m0 = 0, m1 = 0, m2 = 0, m3 = 0;   // |x| bit-pattern max == float max
#pragma unroll 8
    for (int r = 0; r < ROWS_PER_BLOCK; ++r) {
        float4 v = p[(size_t)r * C4];
        m0 = max(m0, __float_as_uint(v.x) & 0x7FFFFFFFu);
        m1 = max(m1, __float_as_uint(v.y) & 0x7FFFFFFFu);
        m2 = max(m2, __float_as_uint(v.z) & 0x7FFFFFFFu);
        m3 = max(m3, __float_as_uint(v.w) & 0x7FFFFFFFu);
    }
    float4 o;
    o.x = __uint_as_float(m0);
    o.y = __uint_as_float(m1);
    o.z = __uint_as_float(m2);
    o.w = __uint_as_float(m3);
    partial4[(size_t)blockIdx.y * C4 + c4] = o;
}

// ---------------------------------------------------------------------------
// Pass 2: reduce 128 partials per column; emit bit-exact forward scale
// (IEEE 448/amax, matches numpy) and the dequant inverse (amax/448).
// ---------------------------------------------------------------------------
__global__ __launch_bounds__(256) void scale_from_partials(const float* __restrict__ partial,
                                                           float* __restrict__ scale,
                                                           float* __restrict__ inv) {
    int c = blockIdx.x * 256 + threadIdx.x;
    float a = 0.0f;
#pragma unroll 8
    for (int k = 0; k < ROWCHUNKS; ++k)
        a = fmaxf(a, partial[(size_t)k * N_COLS + c]);
    a = fmaxf(a, EPS_F);
    scale[c] = FP8_MAX_F / a;   // IEEE divide: must be bit-identical to numpy
    inv[c]   = a / FP8_MAX_F;   // dequant multiplier (1-2 ulp vs q/scale: fine)
}

// ---------------------------------------------------------------------------
// Pass 3: scale -> clip -> HW e4m3fn RNE cast -> dequant-multiply.
// REVERSE chunk traversal: read x tail-first so the re-read hits the data
// pass 1 just left hot in the 256 MiB L3 (forward re-read at capacity==size
// is the LRU worst case). Intra-chunk addressing stays forward/coalesced.
// Non-temporal stores so `out` doesn't evict x from L3.
// ---------------------------------------------------------------------------
__global__ __launch_bounds__(256) void quant_kernel(const float4* __restrict__ x4,
                                                    const float4* __restrict__ scale4,
                                                    const float4* __restrict__ inv4,
                                                    floatx4* __restrict__ out4) {
    const size_t n4 = (size_t)N_ROWS * C4;
    const size_t T = (size_t)QBLOCKS * 256;          // threads in grid
    const int NCHUNK = (int)(n4 / T);                // 32
    size_t gtid = (size_t)blockIdx.x * 256 + threadIdx.x;
    for (int c = NCHUNK - 1; c >= 0; --c) {
        size_t i = (size_t)c * T + gtid;
        size_t ci = i & (size_t)(C4 - 1);
        float4 s = scale4[ci];
        float4 w = inv4[ci];
        float4 v = x4[i];
        float a0 = fminf(fmaxf(v.x * s.x, -FP8_MAX_F), FP8_MAX_F);
        float a1 = fminf(fmaxf(v.y * s.y, -FP8_MAX_F), FP8_MAX_F);
        float a2 = fminf(fmaxf(v.z * s.z, -FP8_MAX_F), FP8_MAX_F);
        float a3 = fminf(fmaxf(v.w * s.w, -FP8_MAX_F), FP8_MAX_F);
        int p = __builtin_amdgcn_cvt_pk_fp8_f32(a0, a1, 0, false);
        p = __builtin_amdgcn_cvt_pk_fp8_f32(a2, a3, p, true);
        floatx4 o;
        o.x = __builtin_amdgcn_cvt_f32_fp8(p, 0) * w.x;
        o.y = __builtin_amdgcn_cvt_f32_fp8(p, 1) * w.y;
        o.z = __builtin_amdgcn_cvt_f32_fp8(p, 2) * w.z;
        o.w = __builtin_amdgcn_cvt_f32_fp8(p, 3) * w.w;
        __builtin_nontemporal_store(o, &out4[i]);
    }
}

extern "C" void kernel_launch(void* const* d_in, const int* in_sizes, int n_in,
                              void* d_out, int out_size, void* d_ws, size_t ws_size,
                              hipStream_t stream) {
    const float* x = (const float*)d_in[0];
    float* out = (float*)d_out;
    // ws: partial (128*8192 f32 = 4 MB) | scale (32 KB) | inv (32 KB)
    float* partial = (float*)d_ws;
    float* scale = (float*)((char*)d_ws + (size_t)ROWCHUNKS * N_COLS * sizeof(float));
    float* inv = scale + N_COLS;

    dim3 g1(N_COLS / 1024, ROWCHUNKS);
    col_amax_partial<<<g1, 256, 0, stream>>>((const float4*)x, (float4*)partial);

    scale_from_partials<<<N_COLS / 256, 256, 0, stream>>>(partial, scale, inv);

    quant_kernel<<<QBLOCKS, 256, 0, stream>>>((const float4*)x, (const float4*)scale,
                                              (const float4*)inv, (floatx4*)out);
}